// Round 11
// baseline (30.392 us; speedup 1.0000x reference)
//
#include <hip/hip_runtime.h>

typedef float f4 __attribute__((ext_vector_type(4)));

#define NJ 24
#define BLK 128
#define OUTW 75               // (NJ+1)*3 floats per row
#define HROWS 32              // rows staged per dump phase (half wave)
#define HBUF (HROWS * OUTW)   // 2400 floats = 9.6 KB per wave
#define CW 12                 // per-joint consts: qA[4], qB[4], xyz[3], halfnorm

// ---- pre-kernel: derive per-joint quaternion constants into d_ws ----
__global__ __launch_bounds__(64) void fk_const_kernel(
    const float* __restrict__ xyz, const float* __restrict__ rpy,
    const float* __restrict__ axis, float* __restrict__ ws)
{
    const int j = threadIdx.x;
    if (j >= NJ) return;
    float r = rpy[j*3+0] * 0.5f, p = rpy[j*3+1] * 0.5f, yv = rpy[j*3+2] * 0.5f;
    float sr, cr, sp, cp, sy, cy;
    __sincosf(r, &sr, &cr);
    __sincosf(p, &sp, &cp);
    __sincosf(yv, &sy, &cy);
    float qw = cr*cp*cy + sr*sp*sy;
    float qx = sr*cp*cy - cr*sp*sy;
    float qy = cr*sp*cy + sr*cp*sy;
    float qz = cr*cp*sy - sr*sp*cy;
    float ax = axis[j*3+0], ay = axis[j*3+1], az = axis[j*3+2];
    float n = sqrtf(ax*ax + ay*ay + az*az);
    float inv = 1.0f / fmaxf(n, 1e-6f);
    float ux = ax*inv, uy = ay*inv, uz = az*inv;
    float* c = ws + j * CW;
    c[0] = qw; c[1] = qx; c[2] = qy; c[3] = qz;          // qA = qRo
    c[4] = -(qx*ux + qy*uy + qz*uz);                      // qB = qRo x (0,u)
    c[5] = qw*ux + qy*uz - qz*uy;
    c[6] = qw*uy + qz*ux - qx*uz;
    c[7] = qw*uz + qx*uy - qy*ux;
    c[8] = xyz[j*3+0]; c[9] = xyz[j*3+1]; c[10] = xyz[j*3+2];
    c[11] = n * 0.5f;
}

__global__ __launch_bounds__(BLK, 4) void fk_main_kernel(
    const float* __restrict__ ang,   // (B, 24)
    const float* __restrict__ cst,   // (24, 12) derived consts in d_ws
    float* __restrict__ out)         // (B, 75)
{
    __shared__ float buf[(BLK / 64) * HBUF];   // 2 x 9.6 KB per-wave regions

    const int tid = threadIdx.x;
    const int wv = tid >> 6, ln = tid & 63;
    float* wbuf = &buf[wv * HBUF];

    // ---- my row's 24 angles via 6x float4 (row base 96B -> 16B aligned) ----
    const long long row = (long long)blockIdx.x * BLK + tid;
    const f4* gA = (const f4*)(ang + row * NJ);
    f4 A[6];
    #pragma unroll
    for (int k = 0; k < 6; ++k) A[k] = gA[k];

    // ---- single FK chain per thread; positions accumulate in REGISTERS.
    //      Per-joint consts come from uniform-address loads (scalar pipe /
    //      L1 broadcast) -> zero DS-pipe cost, no block barrier anywhere. ----
    float o[OUTW];                       // all indices compile-time -> VGPRs
    o[0] = 0.f; o[1] = 0.f; o[2] = 0.f;
    float Qw = 1.f, Qx = 0.f, Qy = 0.f, Qz = 0.f;
    float t0 = 0.f, t1 = 0.f, t2 = 0.f;

    #pragma unroll
    for (int j = 0; j < NJ; ++j) {
        const f4* cj = (const f4*)(cst + j * CW);   // uniform address
        f4 ca = cj[0];   // qA
        f4 cb = cj[1];   // qB
        f4 cv = cj[2];   // xyz, halfnorm
        float h = A[j >> 2][j & 3] * cv.w;
        float s, cq;
        __sincosf(h, &s, &cq);
        float lw = cq*ca.x + s*cb.x;
        float lx = cq*ca.y + s*cb.y;
        float ly = cq*ca.z + s*cb.z;
        float lz = cq*ca.w + s*cb.w;
        float vx = cv.x, vy = cv.y, vz = cv.z;
        float px = Qy*vz - Qz*vy + Qw*vx;
        float py = Qz*vx - Qx*vz + Qw*vy;
        float pz = Qx*vy - Qy*vx + Qw*vz;
        t0 += vx + 2.f*(Qy*pz - Qz*py);
        t1 += vy + 2.f*(Qz*px - Qx*pz);
        t2 += vz + 2.f*(Qx*py - Qy*px);
        float nw = Qw*lw - Qx*lx - Qy*ly - Qz*lz;
        float nx = Qw*lx + Qx*lw + Qy*lz - Qz*ly;
        float ny = Qw*ly - Qx*lz + Qy*lw + Qz*lx;
        float nz = Qw*lz + Qx*ly - Qy*lx + Qz*lw;
        Qw = nw; Qx = nx; Qy = ny; Qz = nz;
        o[3*(j+1)+0] = t0;
        o[3*(j+1)+1] = t1;
        o[3*(j+1)+2] = t2;
    }

    // global f4 base for this wave's 64 rows (64*75*4 = 19200 B contiguous)
    f4* gW = (f4*)(out + ((long long)blockIdx.x * BLK + wv * 64) * OUTW);

    // ---- phase 0: lanes 0..31 stage their full rows; whole wave dumps ----
    // staging addr = ln*75 + k -> bank (11*ln + k) mod 32: bijective in ln
    // -> conflict-free. LDS ptrs deliberately NOT restrict (they alias).
    if (ln < HROWS) {
        float* ob = wbuf + ln * OUTW;
        #pragma unroll
        for (int k = 0; k < OUTW; ++k) ob[k] = o[k];
    }
    asm volatile("" ::: "memory");   // stage-writes -> dump-reads (RAW order)
    {
        const f4* lb = (const f4*)wbuf;          // 600 f4, contiguous
        #pragma unroll
        for (int k = 0; k < 10; ++k) {
            int i = k * 64 + ln;
            if (i < HBUF / 4) gW[i] = lb[i];
        }
    }
    asm volatile("" ::: "memory");   // dump-reads -> phase-1 stage-writes (WAR)

    // ---- phase 1: lanes 32..63 stage; whole wave dumps second half ----
    if (ln >= HROWS) {
        float* ob = wbuf + (ln - HROWS) * OUTW;
        #pragma unroll
        for (int k = 0; k < OUTW; ++k) ob[k] = o[k];
    }
    asm volatile("" ::: "memory");   // stage-writes -> dump-reads (RAW order)
    {
        const f4* lb = (const f4*)wbuf;
        #pragma unroll
        for (int k = 0; k < 10; ++k) {
            int i = k * 64 + ln;
            if (i < HBUF / 4) gW[i + HBUF / 4] = lb[i];
        }
    }
}

extern "C" void kernel_launch(void* const* d_in, const int* in_sizes, int n_in,
                              void* d_out, int out_size, void* d_ws, size_t ws_size,
                              hipStream_t stream) {
    const float* ang  = (const float*)d_in[0];
    const float* xyz  = (const float*)d_in[1];
    const float* rpy  = (const float*)d_in[2];
    const float* axis = (const float*)d_in[3];
    float* out = (float*)d_out;
    float* ws  = (float*)d_ws;           // 288 floats of derived constants

    fk_const_kernel<<<1, 64, 0, stream>>>(xyz, rpy, axis, ws);

    const int B = in_sizes[0] / NJ;          // 262144
    const int grid = B / BLK;                // 2048 = 8 blocks/CU, one round
    fk_main_kernel<<<grid, BLK, 0, stream>>>(ang, ws, out);
}

// Round 12
// 27.445 us; speedup vs baseline: 1.1074x; 1.1074x over previous
//
#include <hip/hip_runtime.h>

typedef float f4 __attribute__((ext_vector_type(4)));

#define NJ 24
#define BLK 128
#define OUTW 75               // (NJ+1)*3 floats per row
#define HROWS 32              // rows staged per dump phase (half wave)
#define HBUF (HROWS * OUTW)   // 2400 floats = 9.6 KB per wave
#define CW 12                 // per-joint consts: qA[4], qB[4], xyz[3], halfnorm

__global__ __launch_bounds__(BLK, 4) void fk_main_kernel(
    const float* __restrict__ ang,   // (B, 24)
    const float* __restrict__ xyz,   // (24, 3)
    const float* __restrict__ rpy,   // (24, 3)
    const float* __restrict__ axis,  // (24, 3)
    float* __restrict__ out)         // (B, 75)
{
    // 2 x 9.6 KB wave-private regions; each wave's region first hosts its own
    // 288-float const table (floats 0..287), later the 32-row staging buffer.
    // Exactly 19200 B -> 8 blocks/CU (vs 20352 -> 7 with a separate lcst).
    __shared__ float buf[(BLK / 64) * HBUF];

    const int tid = threadIdx.x;
    const int wv = tid >> 6, ln = tid & 63;
    float* wbuf = &buf[wv * HBUF];

    // ---- my row's 24 angles via 6x float4 (row base 96B -> 16B aligned) ----
    const long long row = (long long)blockIdx.x * BLK + tid;
    const f4* gA = (const f4*)(ang + row * NJ);
    f4 A[6];
    #pragma unroll
    for (int k = 0; k < 6; ++k) A[k] = gA[k];

    // ---- per-wave consts: lanes 0..23 write joint ln's 12 floats ----
    if (ln < NJ) {
        const int j = ln;
        float r = rpy[j*3+0] * 0.5f, p = rpy[j*3+1] * 0.5f, yv = rpy[j*3+2] * 0.5f;
        float sr, cr, sp, cp, sy, cy;
        __sincosf(r, &sr, &cr);
        __sincosf(p, &sp, &cp);
        __sincosf(yv, &sy, &cy);
        float qw = cr*cp*cy + sr*sp*sy;
        float qx = sr*cp*cy - cr*sp*sy;
        float qy = cr*sp*cy + sr*cp*sy;
        float qz = cr*cp*sy - sr*sp*cy;
        float ax = axis[j*3+0], ay = axis[j*3+1], az = axis[j*3+2];
        float n = sqrtf(ax*ax + ay*ay + az*az);
        float inv = 1.0f / fmaxf(n, 1e-6f);
        float ux = ax*inv, uy = ay*inv, uz = az*inv;
        float* c = wbuf + j * CW;        // wave-private -> no block barrier
        c[0] = qw; c[1] = qx; c[2] = qy; c[3] = qz;        // qA = qRo
        c[4] = -(qx*ux + qy*uy + qz*uz);                    // qB = qRo x (0,u)
        c[5] = qw*ux + qy*uz - qz*uy;
        c[6] = qw*uy + qz*ux - qx*uz;
        c[7] = qw*uz + qx*uy - qy*ux;
        c[8] = xyz[j*3+0]; c[9] = xyz[j*3+1]; c[10] = xyz[j*3+2];
        c[11] = n * 0.5f;
    }
    asm volatile("" ::: "memory");   // const-writes -> chain-reads (RAW, same wave)

    // ---- single FK chain per thread; positions accumulate in REGISTERS ----
    float o[OUTW];                       // all indices compile-time -> VGPRs
    o[0] = 0.f; o[1] = 0.f; o[2] = 0.f;
    float Qw = 1.f, Qx = 0.f, Qy = 0.f, Qz = 0.f;
    float t0 = 0.f, t1 = 0.f, t2 = 0.f;

    #pragma unroll
    for (int j = 0; j < NJ; ++j) {
        const float* cc = wbuf + j * CW;   // wave-uniform -> LDS broadcast
        float h = A[j >> 2][j & 3] * cc[11];
        float s, cq;
        __sincosf(h, &s, &cq);
        float lw = cq*cc[0] + s*cc[4];
        float lx = cq*cc[1] + s*cc[5];
        float ly = cq*cc[2] + s*cc[6];
        float lz = cq*cc[3] + s*cc[7];
        float vx = cc[8], vy = cc[9], vz = cc[10];
        float px = Qy*vz - Qz*vy + Qw*vx;
        float py = Qz*vx - Qx*vz + Qw*vy;
        float pz = Qx*vy - Qy*vx + Qw*vz;
        t0 += vx + 2.f*(Qy*pz - Qz*py);
        t1 += vy + 2.f*(Qz*px - Qx*pz);
        t2 += vz + 2.f*(Qx*py - Qy*px);
        float nw = Qw*lw - Qx*lx - Qy*ly - Qz*lz;
        float nx = Qw*lx + Qx*lw + Qy*lz - Qz*ly;
        float ny = Qw*ly - Qx*lz + Qy*lw + Qz*lx;
        float nz = Qw*lz + Qx*ly - Qy*lx + Qz*lw;
        Qw = nw; Qx = nx; Qy = ny; Qz = nz;
        o[3*(j+1)+0] = t0;
        o[3*(j+1)+1] = t1;
        o[3*(j+1)+2] = t2;
    }

    asm volatile("" ::: "memory");   // last const-read -> stage-writes (WAR)

    // global f4 base for this wave's 64 rows (64*75*4 = 19200 B contiguous)
    f4* gW = (f4*)(out + ((long long)blockIdx.x * BLK + wv * 64) * OUTW);

    // ---- phase 0: lanes 0..31 stage full rows; whole wave dumps 9.6 KB ----
    // staging addr = ln*75 + k -> bank (11*ln + k) mod 32: bijective in ln
    // -> conflict-free. LDS ptrs deliberately NOT restrict (they alias).
    if (ln < HROWS) {
        float* ob = wbuf + ln * OUTW;
        #pragma unroll
        for (int k = 0; k < OUTW; ++k) ob[k] = o[k];
    }
    asm volatile("" ::: "memory");   // stage-writes -> dump-reads (RAW order)
    {
        const f4* lb = (const f4*)wbuf;          // 600 f4, contiguous
        #pragma unroll
        for (int k = 0; k < 10; ++k) {
            int i = k * 64 + ln;
            if (i < HBUF / 4) gW[i] = lb[i];
        }
    }
    asm volatile("" ::: "memory");   // dump-reads -> phase-1 stage-writes (WAR)

    // ---- phase 1: lanes 32..63 stage; whole wave dumps second 9.6 KB ----
    if (ln >= HROWS) {
        float* ob = wbuf + (ln - HROWS) * OUTW;
        #pragma unroll
        for (int k = 0; k < OUTW; ++k) ob[k] = o[k];
    }
    asm volatile("" ::: "memory");   // stage-writes -> dump-reads (RAW order)
    {
        const f4* lb = (const f4*)wbuf;
        #pragma unroll
        for (int k = 0; k < 10; ++k) {
            int i = k * 64 + ln;
            if (i < HBUF / 4) gW[i + HBUF / 4] = lb[i];
        }
    }
}

extern "C" void kernel_launch(void* const* d_in, const int* in_sizes, int n_in,
                              void* d_out, int out_size, void* d_ws, size_t ws_size,
                              hipStream_t stream) {
    const float* ang  = (const float*)d_in[0];
    const float* xyz  = (const float*)d_in[1];
    const float* rpy  = (const float*)d_in[2];
    const float* axis = (const float*)d_in[3];
    float* out = (float*)d_out;

    const int B = in_sizes[0] / NJ;          // 262144
    const int grid = B / BLK;                // 2048 = 8 blocks/CU, one round
    fk_main_kernel<<<grid, BLK, 0, stream>>>(ang, xyz, rpy, axis, out);
}

// Round 13
// 26.201 us; speedup vs baseline: 1.1600x; 1.0475x over previous
//
#include <hip/hip_runtime.h>

typedef float f4 __attribute__((ext_vector_type(4)));

#define NJ 24
#define BLK 128
#define OUTW 75               // (NJ+1)*3 floats per row
#define HROWS 32              // rows staged per dump phase (half wave)
#define HBUF (HROWS * OUTW)   // 2400 floats = 9.6 KB per wave

// broadcast lane j's float to all lanes as wave-uniform SGPR (no DS pipe)
#define RL(v, j) __int_as_float(__builtin_amdgcn_readlane(__float_as_int(v), (j)))

__global__ __launch_bounds__(BLK, 4) void fk_main_kernel(
    const float* __restrict__ ang,   // (B, 24)
    const float* __restrict__ xyz,   // (24, 3)
    const float* __restrict__ rpy,   // (24, 3)
    const float* __restrict__ axis,  // (24, 3)
    float* __restrict__ out)         // (B, 75)
{
    // LDS is ONLY the per-wave staging bounce: 2 x 9.6 KB = 19200 B/block
    __shared__ float buf[(BLK / 64) * HBUF];

    const int tid = threadIdx.x;
    const int wv = tid >> 6, ln = tid & 63;
    float* wbuf = &buf[wv * HBUF];

    // ---- my row's 24 angles via 6x float4 (row base 96B -> 16B aligned) ----
    const long long row = (long long)blockIdx.x * BLK + tid;
    const f4* gA = (const f4*)(ang + row * NJ);
    f4 A[6];
    #pragma unroll
    for (int k = 0; k < 6; ++k) A[k] = gA[k];

    // ---- per-joint consts: lanes 0..23 of EACH wave hold joint ln's 12 ----
    float c0=0,c1=0,c2=0,c3=0,c4=0,c5=0,c6=0,c7=0,c8=0,c9=0,c10=0,c11=0;
    if (ln < NJ) {
        const int j = ln;
        float r = rpy[j*3+0] * 0.5f, p = rpy[j*3+1] * 0.5f, yv = rpy[j*3+2] * 0.5f;
        float sr, cr, sp, cp, sy, cy;
        __sincosf(r, &sr, &cr);
        __sincosf(p, &sp, &cp);
        __sincosf(yv, &sy, &cy);
        float qw = cr*cp*cy + sr*sp*sy;
        float qx = sr*cp*cy - cr*sp*sy;
        float qy = cr*sp*cy + sr*cp*sy;
        float qz = cr*cp*sy - sr*sp*cy;
        float ax = axis[j*3+0], ay = axis[j*3+1], az = axis[j*3+2];
        float n = sqrtf(ax*ax + ay*ay + az*az);
        float inv = 1.0f / fmaxf(n, 1e-6f);
        float ux = ax*inv, uy = ay*inv, uz = az*inv;
        c0 = qw; c1 = qx; c2 = qy; c3 = qz;            // qA = qRo
        c4 = -(qx*ux + qy*uy + qz*uz);                  // qB = qRo x (0,u)
        c5 = qw*ux + qy*uz - qz*uy;
        c6 = qw*uy + qz*ux - qx*uz;
        c7 = qw*uz + qx*uy - qy*ux;
        c8 = xyz[j*3+0]; c9 = xyz[j*3+1]; c10 = xyz[j*3+2];
        c11 = n * 0.5f;
    }

    // ---- single FK chain per thread; consts via readlane (SGPR), zero DS ----
    float o[OUTW];                       // all indices compile-time -> VGPRs
    o[0] = 0.f; o[1] = 0.f; o[2] = 0.f;
    float Qw = 1.f, Qx = 0.f, Qy = 0.f, Qz = 0.f;
    float t0 = 0.f, t1 = 0.f, t2 = 0.f;

    #pragma unroll
    for (int j = 0; j < NJ; ++j) {
        float qa0 = RL(c0, j), qa1 = RL(c1, j), qa2 = RL(c2, j), qa3 = RL(c3, j);
        float qb0 = RL(c4, j), qb1 = RL(c5, j), qb2 = RL(c6, j), qb3 = RL(c7, j);
        float vx  = RL(c8, j), vy  = RL(c9, j), vz  = RL(c10, j);
        float hn  = RL(c11, j);

        float h = A[j >> 2][j & 3] * hn;
        float s, cq;
        __sincosf(h, &s, &cq);
        // each FMA below reads at most ONE SGPR operand -> no extra v_movs
        float lw = cq*qa0 + s*qb0;
        float lx = cq*qa1 + s*qb1;
        float ly = cq*qa2 + s*qb2;
        float lz = cq*qa3 + s*qb3;
        float px = Qy*vz - Qz*vy + Qw*vx;
        float py = Qz*vx - Qx*vz + Qw*vy;
        float pz = Qx*vy - Qy*vx + Qw*vz;
        t0 += vx + 2.f*(Qy*pz - Qz*py);
        t1 += vy + 2.f*(Qz*px - Qx*pz);
        t2 += vz + 2.f*(Qx*py - Qy*px);
        float nw = Qw*lw - Qx*lx - Qy*ly - Qz*lz;
        float nx = Qw*lx + Qx*lw + Qy*lz - Qz*ly;
        float ny = Qw*ly - Qx*lz + Qy*lw + Qz*lx;
        float nz = Qw*lz + Qx*ly - Qy*lx + Qz*lw;
        Qw = nw; Qx = nx; Qy = ny; Qz = nz;
        o[3*(j+1)+0] = t0;
        o[3*(j+1)+1] = t1;
        o[3*(j+1)+2] = t2;
    }

    // global f4 base for this wave's 64 rows (64*75*4 = 19200 B contiguous)
    f4* gW = (f4*)(out + ((long long)blockIdx.x * BLK + wv * 64) * OUTW);

    // ---- phase 0: lanes 0..31 stage full rows; whole wave dumps 9.6 KB ----
    // staging addr = ln*75 + k -> bank (11*ln + k) mod 32: bijective in ln
    // -> conflict-free. LDS ptrs deliberately NOT restrict (they alias).
    if (ln < HROWS) {
        float* ob = wbuf + ln * OUTW;
        #pragma unroll
        for (int k = 0; k < OUTW; ++k) ob[k] = o[k];
    }
    asm volatile("" ::: "memory");   // stage-writes -> dump-reads (RAW order)
    {
        const f4* lb = (const f4*)wbuf;          // 600 f4, contiguous
        #pragma unroll
        for (int k = 0; k < 10; ++k) {
            int i = k * 64 + ln;
            if (i < HBUF / 4) gW[i] = lb[i];
        }
    }
    asm volatile("" ::: "memory");   // dump-reads -> phase-1 stage-writes (WAR)

    // ---- phase 1: lanes 32..63 stage; whole wave dumps second 9.6 KB ----
    if (ln >= HROWS) {
        float* ob = wbuf + (ln - HROWS) * OUTW;
        #pragma unroll
        for (int k = 0; k < OUTW; ++k) ob[k] = o[k];
    }
    asm volatile("" ::: "memory");   // stage-writes -> dump-reads (RAW order)
    {
        const f4* lb = (const f4*)wbuf;
        #pragma unroll
        for (int k = 0; k < 10; ++k) {
            int i = k * 64 + ln;
            if (i < HBUF / 4) gW[i + HBUF / 4] = lb[i];
        }
    }
}

extern "C" void kernel_launch(void* const* d_in, const int* in_sizes, int n_in,
                              void* d_out, int out_size, void* d_ws, size_t ws_size,
                              hipStream_t stream) {
    const float* ang  = (const float*)d_in[0];
    const float* xyz  = (const float*)d_in[1];
    const float* rpy  = (const float*)d_in[2];
    const float* axis = (const float*)d_in[3];
    float* out = (float*)d_out;

    const int B = in_sizes[0] / NJ;          // 262144
    const int grid = B / BLK;                // 2048 = 8 blocks/CU, one round
    fk_main_kernel<<<grid, BLK, 0, stream>>>(ang, xyz, rpy, axis, out);
}